// Round 11
// baseline (895.424 us; speedup 1.0000x reference)
//
#include <hip/hip_runtime.h>

#define HW 1024
#define NIMG 32
#define IMGPX ((size_t)HW * HW)
#define NELEM (NIMG * IMGPX)

typedef float f2 __attribute__((ext_vector_type(2)));

// Wave-autonomous temporal blocking: one 64-lane wave owns a 64-col x 40-row
// region in REGISTERS (1 col/lane, rows as f2 pairs). 7 steps, no barriers,
// no LDS tiles. Horizontal halo via ds_bpermute; vertical = register renames.
// Frozen top/bottom pairs + lane-edge wrap garbage consumed by ring 6.
#define NSP 20      // staged row pairs: rows oy-2 .. oy+37
#define NUP 18      // updated pairs 1..18 = rows oy+0 .. oy+35
#define OUTC 50     // output lanes 7..56
#define OUTR 24     // output rows oy+6 .. oy+29
#define CT 21       // ceil(1024/50)
#define RT 43       // ceil(1024/24)

// ---- float <-> order-preserving unsigned (for atomic min/max) ----
__device__ __forceinline__ unsigned f2su(float f) {
    unsigned u = __float_as_uint(f);
    return (u & 0x80000000u) ? ~u : (u | 0x80000000u);
}
__device__ __forceinline__ float s2f(unsigned u) {
    return __uint_as_float((u & 0x80000000u) ? (u & 0x7fffffffu) : ~u);
}

__global__ void mm_init(unsigned* mm) {
    mm[0] = 0xFFFFFFFFu;
    mm[1] = 0u;
}

__global__ __launch_bounds__(256) void mm_reduce(const float4* __restrict__ x,
                                                 unsigned* mm, int n4) {
    const int tid = threadIdx.x;
    int gid = blockIdx.x * blockDim.x + tid;
    const int stride = gridDim.x * blockDim.x;
    float vmin = 3.4e38f, vmax = -3.4e38f;
    for (int i = gid; i < n4; i += stride) {
        float4 v = x[i];
        vmin = fminf(vmin, fminf(fminf(v.x, v.y), fminf(v.z, v.w)));
        vmax = fmaxf(vmax, fmaxf(fmaxf(v.x, v.y), fmaxf(v.z, v.w)));
    }
    __shared__ float smin[256];
    __shared__ float smax[256];
    smin[tid] = vmin; smax[tid] = vmax;
    __syncthreads();
    for (int s = 128; s > 0; s >>= 1) {
        if (tid < s) {
            smin[tid] = fminf(smin[tid], smin[tid + s]);
            smax[tid] = fmaxf(smax[tid], smax[tid + s]);
        }
        __syncthreads();
    }
    if (tid == 0) {
        atomicMin(&mm[0], f2su(smin[0]));
        atomicMax(&mm[1], f2su(smax[0]));
    }
}

__device__ __forceinline__ f2 shfl2(f2 v, int l) {
    return f2{__shfl(v.x, l), __shfl(v.y, l)};
}

// One conv application over pair-chunks, exact numpy row-major per-element
// order: (r-1,c-1),(r-1,c),(r-1,c+1),(r,c-1),(r,c),(r,c+1),(r+1,*)
#define CONV9(ACC, W)                                          \
    do {                                                       \
        ACC = ACC + f2{W[0], W[0]} * Al;                       \
        ACC = ACC + f2{W[1], W[1]} * Ac;                       \
        ACC = ACC + f2{W[2], W[2]} * Ar;                       \
        ACC = ACC + f2{W[3], W[3]} * plC;                      \
        ACC = ACC + f2{W[4], W[4]} * pcC;                      \
        ACC = ACC + f2{W[5], W[5]} * prC;                      \
        ACC = ACC + f2{W[6], W[6]} * Cl;                       \
        ACC = ACC + f2{W[7], W[7]} * Cc;                       \
        ACC = ACC + f2{W[8], W[8]} * Cr;                       \
    } while (0)

template <int FIRST, int LAST>
__global__ __launch_bounds__(64) void fused_k(
    const float* __restrict__ x, const float* __restrict__ sin_,
    float* __restrict__ sout, const unsigned* __restrict__ mm,
    const float* __restrict__ wAp, const float* __restrict__ wBp,
    const float* __restrict__ biasp) {
#pragma clang fp contract(off)
    const int lane = threadIdx.x;
    const int laneL = (lane + 63) & 63;
    const int laneR = (lane + 1) & 63;
    const int ox = (int)blockIdx.x * OUTC - 7;
    const int oy = (int)blockIdx.y * OUTR - 6;
    const int gc = ox + lane;
    const size_t img = (size_t)blockIdx.z * IMGPX;
    const bool intr = (ox >= 0) & (ox + 63 < HW) & (oy >= 2) & (oy + 37 < HW);
    const bool colIn = (gc >= 0) & (gc < HW);

    const float xmin = s2f(mm[0]);
    const float xmax = s2f(mm[1]);
    const float scale = 2.0f / (xmax - xmin);
    const float b = biasp[0];
    const f2 b2 = f2{b, b};
    const float mc = colIn ? 1.0f : 0.0f;
    const f2 mc2 = f2{mc, mc};

    // ---- stage xn into S (vertical pairs: S[j] = rows oy-2+2j, oy-1+2j) ----
    f2 S[NSP];
    {
        const float* bp = x + img + (size_t)(oy - 2) * HW + gc;
        if (intr) {
#pragma unroll
            for (int j = 0; j < NSP; ++j) {
                const float a0 = bp[(size_t)(2 * j) * HW];
                const float a1 = bp[(size_t)(2 * j + 1) * HW];
                S[j] = f2{(a0 - xmin) * scale - 1.0f, (a1 - xmin) * scale - 1.0f};
            }
        } else {
#pragma unroll
            for (int j = 0; j < NSP; ++j) {
                const int r0 = oy - 2 + 2 * j, r1 = r0 + 1;
                float v0 = 0.0f, v1 = 0.0f;
                if (colIn & (r0 >= 0) & (r0 < HW))
                    v0 = (x[img + (size_t)r0 * HW + gc] - xmin) * scale - 1.0f;
                if (colIn & (r1 >= 0) & (r1 < HW))
                    v1 = (x[img + (size_t)r1 * HW + gc] - xmin) * scale - 1.0f;
                S[j] = f2{v0, v1};
            }
        }
    }

    // ---- BU = conv(xn, B) for updated pairs (exact for all in-image px) ----
    f2 BU[NUP];
    {
        float cw[9];
#pragma unroll
        for (int j = 0; j < 9; ++j) cw[j] = wBp[j];
        f2 plP = shfl2(S[0], laneL), prP = shfl2(S[0], laneR);
        f2 plC = shfl2(S[1], laneL), prC = shfl2(S[1], laneR);
        f2 pcP = S[0];
#pragma unroll
        for (int i = 1; i <= NUP; ++i) {
            const f2 plN = shfl2(S[i + 1], laneL), prN = shfl2(S[i + 1], laneR);
            const f2 pcC = S[i], pcN = S[i + 1];
            const f2 Al = f2{plP.y, plC.x}, Ac = f2{pcP.y, pcC.x}, Ar = f2{prP.y, prC.x};
            const f2 Cl = f2{plC.y, plN.x}, Cc = f2{pcC.y, pcN.x}, Cr = f2{prC.y, prN.x};
            f2 acc = f2{0.0f, 0.0f};
            CONV9(acc, cw);
            BU[i - 1] = acc;
            plP = plC; plC = plN; prP = prC; prC = prN; pcP = pcC;
        }
    }

    // ---- stage s (kernels 2,3) or zeros (kernel 1) ----
    if (FIRST) {
#pragma unroll
        for (int j = 0; j < NSP; ++j) S[j] = f2{0.0f, 0.0f};
        // pre-advance step 1: conv(A, zeros) == +0 exactly -> v = (0+b)+BU
#pragma unroll
        for (int i = 1; i <= NUP; ++i) {
            f2 v = (f2{0.0f, 0.0f} + b2) + BU[i - 1];
            v = __builtin_elementwise_max(v, f2{-1.0f, -1.0f});
            v = __builtin_elementwise_min(v, f2{1.0f, 1.0f});
            if (!intr) {
                const int r0 = oy + 2 * i - 2, r1 = r0 + 1;
                const f2 mr = f2{(r0 >= 0 && r0 < HW) ? 1.0f : 0.0f,
                                 (r1 >= 0 && r1 < HW) ? 1.0f : 0.0f};
                v = v * mr;
                v = v * mc2;
            }
            S[i] = v;
        }
    } else {
        const float* sp = sin_ + img + (size_t)(oy - 2) * HW + gc;
        if (intr) {
#pragma unroll
            for (int j = 0; j < NSP; ++j)
                S[j] = f2{sp[(size_t)(2 * j) * HW], sp[(size_t)(2 * j + 1) * HW]};
        } else {
#pragma unroll
            for (int j = 0; j < NSP; ++j) {
                const int r0 = oy - 2 + 2 * j, r1 = r0 + 1;
                float v0 = 0.0f, v1 = 0.0f;
                if (colIn & (r0 >= 0) & (r0 < HW)) v0 = sin_[img + (size_t)r0 * HW + gc];
                if (colIn & (r1 >= 0) & (r1 < HW)) v1 = sin_[img + (size_t)r1 * HW + gc];
                S[j] = f2{v0, v1};
            }
        }
    }

    // ---- step loop: no barriers, no LDS tiles; state in registers ----
    float ca[9];
#pragma unroll
    for (int j = 0; j < 9; ++j) ca[j] = wAp[j];

    const int t0 = FIRST ? 1 : 0;
#pragma unroll 1
    for (int t = t0; t < 7; ++t) {
        f2 plP = shfl2(S[0], laneL), prP = shfl2(S[0], laneR);
        f2 plC = shfl2(S[1], laneL), prC = shfl2(S[1], laneR);
        f2 pcP = S[0];  // frozen pair, never overwritten
#pragma unroll
        for (int i = 1; i <= NUP; ++i) {
            const f2 plN = shfl2(S[i + 1], laneL), prN = shfl2(S[i + 1], laneR);
            const f2 pcC = S[i];          // old value (saved before overwrite)
            const f2 pcN = S[i + 1];      // still old (overwritten next iter)
            const f2 Al = f2{plP.y, plC.x}, Ac = f2{pcP.y, pcC.x}, Ar = f2{prP.y, prC.x};
            const f2 Cl = f2{plC.y, plN.x}, Cc = f2{pcC.y, pcN.x}, Cr = f2{prC.y, prN.x};
            f2 acc = f2{0.0f, 0.0f};
            CONV9(acc, ca);
            f2 v = (acc + b2) + BU[i - 1];
            v = __builtin_elementwise_max(v, f2{-1.0f, -1.0f});
            v = __builtin_elementwise_min(v, f2{1.0f, 1.0f});
            if (!intr) {
                const int r0 = oy + 2 * i - 2, r1 = r0 + 1;
                const f2 mr = f2{(r0 >= 0 && r0 < HW) ? 1.0f : 0.0f,
                                 (r1 >= 0 && r1 < HW) ? 1.0f : 0.0f};
                v = v * mr;
                v = v * mc2;
            }
            S[i] = v;
            plP = plC; plC = plN; prP = prC; prC = prN; pcP = pcC;
        }
    }

    // ---- store: lanes 7..56, pairs 4..15 (rows oy+6 .. oy+29) ----
    if ((lane >= 7) & (lane <= 56) & (gc < HW)) {
#pragma unroll
        for (int i = 4; i <= 15; ++i) {
            const int r0 = oy + 2 * i - 2;
            const int r1 = r0 + 1;
            f2 v = S[i];
            if (LAST) v = (v + f2{1.0f, 1.0f}) * f2{0.5f, 0.5f};
            if (r0 < HW) sout[img + (size_t)r0 * HW + gc] = v.x;
            if (r1 < HW) sout[img + (size_t)r1 * HW + gc] = v.y;
        }
    }
}

extern "C" void kernel_launch(void* const* d_in, const int* in_sizes, int n_in,
                              void* d_out, int out_size, void* d_ws, size_t ws_size,
                              hipStream_t stream) {
    const float* x = (const float*)d_in[0];
    const float* wA = (const float*)d_in[1];
    const float* wB = (const float*)d_in[2];
    const float* bias = (const float*)d_in[3];
    float* out = (float*)d_out;
    unsigned* mm = (unsigned*)d_ws;
    float* pong = (float*)((char*)d_ws + 1024);  // 128 MiB f32 buffer

    mm_init<<<1, 1, 0, stream>>>(mm);
    mm_reduce<<<2048, 256, 0, stream>>>((const float4*)x, mm, (int)(NELEM / 4));

    dim3 grid(CT, RT, NIMG);
    // steps 1-7: zeros -> out (scratch); 8-14: out -> pong; 15-21: pong -> out
    fused_k<1, 0><<<grid, 64, 0, stream>>>(x, nullptr, out, mm, wA, wB, bias);
    fused_k<0, 0><<<grid, 64, 0, stream>>>(x, out, pong, mm, wA, wB, bias);
    fused_k<0, 1><<<grid, 64, 0, stream>>>(x, pong, out, mm, wA, wB, bias);
}

// Round 12
// 862.952 us; speedup vs baseline: 1.0376x; 1.0376x over previous
//
#include <hip/hip_runtime.h>

#define HW 1024
#define NIMG 32
#define IMGPX ((size_t)HW * HW)
#define NELEM (NIMG * IMGPX)

typedef float f2 __attribute__((ext_vector_type(2)));

// region 128x64 per block, ring 6 -> out 116x52. 256 threads, 8 rows/thread.
#define RING 6
#define TOX 116
#define TOY 52
#define NBX 9
#define NBY 20
#define LSTR 136    // words per slot; col c(0..127)->word c; col -1 ->130; col 128 ->131
#define SLOTS 18    // boundary rows per buffer: -1, {0,7 mod 8}x8, 64
#define BUFW (SLOTS * LSTR)

// ---- float <-> order-preserving unsigned (for atomic min/max) ----
__device__ __forceinline__ unsigned f2su(float f) {
    unsigned u = __float_as_uint(f);
    return (u & 0x80000000u) ? ~u : (u | 0x80000000u);
}
__device__ __forceinline__ float s2f(unsigned u) {
    return __uint_as_float((u & 0x80000000u) ? (u & 0x7fffffffu) : ~u);
}

__global__ void mm_init(unsigned* mm) {
    mm[0] = 0xFFFFFFFFu;
    mm[1] = 0u;
}

__global__ __launch_bounds__(256) void mm_reduce(const float4* __restrict__ x,
                                                 unsigned* mm, int n4) {
    const int tid = threadIdx.x;
    int gid = blockIdx.x * blockDim.x + tid;
    const int stride = gridDim.x * blockDim.x;
    float vmin = 3.4e38f, vmax = -3.4e38f;
    for (int i = gid; i < n4; i += stride) {
        float4 v = x[i];
        vmin = fminf(vmin, fminf(fminf(v.x, v.y), fminf(v.z, v.w)));
        vmax = fmaxf(vmax, fmaxf(fmaxf(v.x, v.y), fmaxf(v.z, v.w)));
    }
    __shared__ float smin[256];
    __shared__ float smax[256];
    smin[tid] = vmin; smax[tid] = vmax;
    __syncthreads();
    for (int s = 128; s > 0; s >>= 1) {
        if (tid < s) {
            smin[tid] = fminf(smin[tid], smin[tid + s]);
            smax[tid] = fmaxf(smax[tid], smax[tid + s]);
        }
        __syncthreads();
    }
    if (tid == 0) {
        atomicMin(&mm[0], f2su(smin[0]));
        atomicMax(&mm[1], f2su(smax[0]));
    }
}

struct RowW { f2 P[2]; float L, R; };

// 256 threads: tx 0..31 owns 4 cols (2 f2 pairs), tyg 0..7 owns 8 rows.
// State in registers; double-buffered boundary slots (2 x 9.8 KB LDS).
template <int FIRST, int LAST>
__global__ __launch_bounds__(256) void fused_k(
    const float* __restrict__ x, const float* __restrict__ sin_,
    float* __restrict__ sout, const unsigned* __restrict__ mm,
    const float* __restrict__ wAp, const float* __restrict__ wBp,
    const float* __restrict__ biasp) {
#pragma clang fp contract(off)
    __shared__ float sb[2 * BUFW];
    const int tid = threadIdx.x;
    const int tx = tid & 31;
    const int tyg = tid >> 5;          // 0..7
    const int lane = tid & 63;
    const int laneL = (lane + 63) & 63;
    const int laneR = (lane + 1) & 63;
    const int r0 = tyg << 3;           // 8 rows per thread
    const int c0 = tx << 2;
    const int bx = (int)blockIdx.x, by = (int)blockIdx.y;
    const int ox = bx * TOX - RING;
    const int oy = by * TOY - RING;
    const size_t img = (size_t)blockIdx.z * IMGPX;
    const bool edgeX = (bx == 0) | (bx == NBX - 1);
    const bool edgeY = (by == 0) | (by == NBY - 1);
    const bool intr = !(edgeX | edgeY);

    const float xmin = s2f(mm[0]);
    const float xmax = s2f(mm[1]);
    const float scale = 2.0f / (xmax - xmin);
    const float b = biasp[0];

    auto ldSlot = [&](int wb) -> RowW {
        RowW o;
        const float4 q0 = *reinterpret_cast<const float4*>(&sb[wb + c0]);
        o.P[0] = f2{q0.x, q0.y}; o.P[1] = f2{q0.z, q0.w};
        const float fromL = __shfl(q0.w, laneL);
        const float fromR = __shfl(q0.x, laneR);
        o.L = (tx == 0) ? sb[wb + 130] : fromL;
        o.R = (tx == 31) ? sb[wb + 131] : fromR;
        return o;
    };

    float cf[9];
    // 9-term sequential row-major conv for pixel pair p in {0,1} (exact numpy order)
    auto conv9 = [&](const RowW& A, const RowW& B, const RowW& C, int p) -> f2 {
#pragma clang fp contract(off)
        f2 acc = f2{0.0f, 0.0f};
        f2 tl, tr;
        tl = f2{(p == 0) ? A.L : A.P[0].y, A.P[p].x};
        tr = f2{A.P[p].y, (p == 0) ? A.P[1].x : A.R};
        acc = acc + f2{cf[0], cf[0]} * tl;
        acc = acc + f2{cf[1], cf[1]} * A.P[p];
        acc = acc + f2{cf[2], cf[2]} * tr;
        tl = f2{(p == 0) ? B.L : B.P[0].y, B.P[p].x};
        tr = f2{B.P[p].y, (p == 0) ? B.P[1].x : B.R};
        acc = acc + f2{cf[3], cf[3]} * tl;
        acc = acc + f2{cf[4], cf[4]} * B.P[p];
        acc = acc + f2{cf[5], cf[5]} * tr;
        tl = f2{(p == 0) ? C.L : C.P[0].y, C.P[p].x};
        tr = f2{C.P[p].y, (p == 0) ? C.P[1].x : C.R};
        acc = acc + f2{cf[6], cf[6]} * tl;
        acc = acc + f2{cf[7], cf[7]} * C.P[p];
        acc = acc + f2{cf[8], cf[8]} * tr;
        return acc;
    };

    // stage 34 consecutive xn rows (starting region row row0s) into slots 0..33
    auto stageXn = [&](int row0s) {
        if (intr) {
            for (int k = tid; k < 34 * 130; k += 256) {
                const int si = k / 130;
                const int cc = (k - si * 130) - 1;
                const int w = (cc == -1) ? 130 : ((cc == 128) ? 131 : cc);
                const float v =
                    (x[img + (size_t)(oy + row0s + si) * HW + (ox + cc)] - xmin) * scale - 1.0f;
                sb[si * LSTR + w] = v;
            }
        } else {
            for (int k = tid; k < 34 * 130; k += 256) {
                const int si = k / 130;
                const int cc = (k - si * 130) - 1;
                const int w = (cc == -1) ? 130 : ((cc == 128) ? 131 : cc);
                const int gr = oy + row0s + si;
                const int gc = ox + cc;
                float v = 0.0f;
                if (gr >= 0 && gr < HW && gc >= 0 && gc < HW)
                    v = (x[img + (size_t)gr * HW + gc] - xmin) * scale - 1.0f;
                sb[si * LSTR + w] = v;
            }
        }
    };

    // ---- phase 1+2: BU = conv(xn, B), two 34-row half passes ----
#pragma unroll
    for (int i = 0; i < 9; ++i) cf[i] = wBp[i];
    f2 bu[8][2];
    {
        stageXn(-1);          // rows -1..32 -> slot row+1
        __syncthreads();
        if (tyg < 4) {        // rows r0-1..r0+8 in [-1,32]; slot = row+1
            RowW prev = ldSlot((r0) * LSTR);
            RowW cur = ldSlot((r0 + 1) * LSTR);
#pragma unroll
            for (int i = 0; i < 8; ++i) {
                RowW nxt = ldSlot((r0 + 2 + i) * LSTR);
                bu[i][0] = conv9(prev, cur, nxt, 0);
                bu[i][1] = conv9(prev, cur, nxt, 1);
                prev = cur; cur = nxt;
            }
        }
        __syncthreads();
        stageXn(31);          // rows 31..64 -> slot row-31
        __syncthreads();
        if (tyg >= 4) {       // rows r0-1..r0+8 in [31,64]; slot = row-31
            const int s0 = r0 - 32;
            RowW prev = ldSlot((s0) * LSTR);
            RowW cur = ldSlot((s0 + 1) * LSTR);
#pragma unroll
            for (int i = 0; i < 8; ++i) {
                RowW nxt = ldSlot((s0 + 2 + i) * LSTR);
                bu[i][0] = conv9(prev, cur, nxt, 0);
                bu[i][1] = conv9(prev, cur, nxt, 1);
                prev = cur; cur = nxt;
            }
        }
        __syncthreads();
    }

    // ---- phase 3: stage s into registers + frozen halos into BOTH buffers ----
    // slot map (per buffer): row -1 -> 0; row 8k -> 2k+1; row 8k+7 -> 2k+2; row 64 -> 17
    f2 res[8][2];
    float hS[8];  // tx==0: left halo col; tx==31: right halo col
    for (int k = tid; k < 292; k += 256) {
        int rr, cc;
        if (k < 260) { rr = (k < 130) ? -1 : 64; cc = (k % 130) - 1; }
        else {
            const int kk = k - 260;
            const int s = kk >> 1;            // 0..15
            rr = (s & 1) ? ((s >> 1) * 8 + 7) : ((s >> 1) * 8);
            cc = (kk & 1) ? 128 : -1;
        }
        const int w = (cc == -1) ? 130 : ((cc == 128) ? 131 : cc);
        const int slot = (rr == -1) ? 0 : ((rr == 64) ? 17 : ((rr >> 3) * 2 + 1 + (((rr & 7) == 7) ? 1 : 0)));
        float v = 0.0f;
        if (!FIRST) {
            const int gr = oy + rr, gc = ox + cc;
            if (gr >= 0 && gr < HW && gc >= 0 && gc < HW)
                v = sin_[img + (size_t)gr * HW + gc];
        }
        const int wo = slot * LSTR + w;
        sb[wo] = v;
        sb[BUFW + wo] = v;
    }
    if (FIRST) {
#pragma unroll
        for (int i = 0; i < 8; ++i) {
            hS[i] = 0.0f;
            res[i][0] = f2{0.0f, 0.0f};
            res[i][1] = f2{0.0f, 0.0f};
        }
    } else if (intr) {
#pragma unroll
        for (int i = 0; i < 8; ++i) {
            const float2* src = reinterpret_cast<const float2*>(
                &sin_[img + (size_t)(oy + r0 + i) * HW + ox + c0]);
            const float2 t0 = src[0];
            const float2 t1 = src[1];
            res[i][0] = f2{t0.x, t0.y};
            res[i][1] = f2{t1.x, t1.y};
            float hv = 0.0f;
            if (tx == 0) hv = sin_[img + (size_t)(oy + r0 + i) * HW + (ox - 1)];
            else if (tx == 31) hv = sin_[img + (size_t)(oy + r0 + i) * HW + (ox + 128)];
            hS[i] = hv;
        }
    } else {
#pragma unroll
        for (int i = 0; i < 8; ++i) {
            const int gr = oy + r0 + i;
            const bool rin = (gr >= 0) & (gr < HW);
#pragma unroll
            for (int cl = 0; cl < 4; ++cl) {
                const int gc = ox + c0 + cl;
                float v = 0.0f;
                if (rin && gc >= 0 && gc < HW) v = sin_[img + (size_t)gr * HW + gc];
                res[i][cl >> 1][cl & 1] = v;
            }
            float hv = 0.0f;
            if (tx == 0) {
                const int gc = ox - 1;
                if (rin && gc >= 0) hv = sin_[img + (size_t)gr * HW + gc];
            } else if (tx == 31) {
                const int gc = ox + 128;
                if (rin && gc < HW) hv = sin_[img + (size_t)gr * HW + gc];
            }
            hS[i] = hv;
        }
    }

    auto wrRow = [&](int bo, int i, int slot) {
        *reinterpret_cast<float4*>(&sb[bo + slot * LSTR + c0]) =
            make_float4(res[i][0].x, res[i][0].y, res[i][1].x, res[i][1].y);
    };
    wrRow(0, 0, 2 * tyg + 1);
    wrRow(0, 7, 2 * tyg + 2);
    __syncthreads();

    // ---- phase 4: 7 fused steps, one barrier each ----
#pragma unroll
    for (int i = 0; i < 9; ++i) cf[i] = wAp[i];
    f2 mC2[2];
#pragma unroll
    for (int p = 0; p < 2; ++p) {
        const int g0 = ox + c0 + 2 * p, g1 = g0 + 1;
        mC2[p] = f2{(g0 >= 0 && g0 < HW) ? 1.0f : 0.0f,
                    (g1 >= 0 && g1 < HW) ? 1.0f : 0.0f};
    }

    auto buildRow = [&](const f2 pr[2], float hs) -> RowW {
        RowW o;
        o.P[0] = pr[0]; o.P[1] = pr[1];
        const float fromL = __shfl(pr[1].y, laneL);
        const float fromR = __shfl(pr[0].x, laneR);
        o.L = (tx == 0) ? hs : fromL;
        o.R = (tx == 31) ? hs : fromR;
        return o;
    };

    const int slotM1 = (tyg == 0) ? 0 : 2 * tyg;
    const int slotP8 = (tyg == 7) ? 17 : 2 * tyg + 3;

#pragma unroll 1
    for (int t = 0; t < 7; ++t) {
        const int rdo = (t & 1) * BUFW;
        const int wro = BUFW - rdo;
        RowW prev = ldSlot(rdo + slotM1 * LSTR);   // old row r0-1
        RowW cur = buildRow(res[0], hS[0]);
#pragma unroll
        for (int i = 0; i < 8; ++i) {
            RowW nxt = (i < 7) ? buildRow(res[i + 1], hS[i + 1])
                               : ldSlot(rdo + slotP8 * LSTR);  // old row r0+8
            f2 n0 = conv9(prev, cur, nxt, 0);
            f2 n1 = conv9(prev, cur, nxt, 1);
            n0 = (n0 + f2{b, b}) + bu[i][0];
            n1 = (n1 + f2{b, b}) + bu[i][1];
            n0 = __builtin_elementwise_max(n0, f2{-1.0f, -1.0f});
            n0 = __builtin_elementwise_min(n0, f2{1.0f, 1.0f});
            n1 = __builtin_elementwise_max(n1, f2{-1.0f, -1.0f});
            n1 = __builtin_elementwise_min(n1, f2{1.0f, 1.0f});
            if (!intr) {
                const int gr = oy + r0 + i;
                const float m = (gr >= 0 && gr < HW) ? 1.0f : 0.0f;
                n0 = n0 * f2{m, m};
                n1 = n1 * f2{m, m};
                n0 = n0 * mC2[0];
                n1 = n1 * mC2[1];
            }
            prev = cur; cur = nxt;
            res[i][0] = n0; res[i][1] = n1;
        }
        wrRow(wro, 0, 2 * tyg + 1);
        wrRow(wro, 7, 2 * tyg + 2);
        __syncthreads();
    }

    // ---- phase 5: store inner 116x52 tile ----
    const bool fullc = intr && (c0 >= RING) && (c0 + 3 < RING + TOX);
#pragma unroll
    for (int i = 0; i < 8; ++i) {
        const int r = r0 + i;
        if (r < RING || r >= RING + TOY) continue;
        const int gr = oy + r;
        if (gr >= HW) continue;  // gr >= 0 guaranteed
        if (fullc) {
            float2* dst = reinterpret_cast<float2*>(&sout[img + (size_t)gr * HW + ox + c0]);
            f2 v0 = res[i][0], v1 = res[i][1];
            if (LAST) {
                v0 = (v0 + f2{1.0f, 1.0f}) * f2{0.5f, 0.5f};
                v1 = (v1 + f2{1.0f, 1.0f}) * f2{0.5f, 0.5f};
            }
            dst[0] = make_float2(v0.x, v0.y);
            dst[1] = make_float2(v1.x, v1.y);
        } else {
#pragma unroll
            for (int cl = 0; cl < 4; ++cl) {
                const int c = c0 + cl;
                if (c < RING || c >= RING + TOX) continue;
                const int gc = ox + c;
                if (gc < 0 || gc >= HW) continue;
                float v = res[i][cl >> 1][cl & 1];
                if (LAST) v = (v + 1.0f) * 0.5f;
                sout[img + (size_t)gr * HW + gc] = v;
            }
        }
    }
}

extern "C" void kernel_launch(void* const* d_in, const int* in_sizes, int n_in,
                              void* d_out, int out_size, void* d_ws, size_t ws_size,
                              hipStream_t stream) {
    const float* x = (const float*)d_in[0];
    const float* wA = (const float*)d_in[1];
    const float* wB = (const float*)d_in[2];
    const float* bias = (const float*)d_in[3];
    float* out = (float*)d_out;
    unsigned* mm = (unsigned*)d_ws;
    float* pong = (float*)((char*)d_ws + 1024);  // 128 MiB f32 buffer

    mm_init<<<1, 1, 0, stream>>>(mm);
    mm_reduce<<<2048, 256, 0, stream>>>((const float4*)x, mm, (int)(NELEM / 4));

    dim3 grid(NBX, NBY, NIMG);
    // steps 1-7: zeros -> out (scratch); 8-14: out -> pong; 15-21: pong -> out
    fused_k<1, 0><<<grid, 256, 0, stream>>>(x, nullptr, out, mm, wA, wB, bias);
    fused_k<0, 0><<<grid, 256, 0, stream>>>(x, out, pong, mm, wA, wB, bias);
    fused_k<0, 1><<<grid, 256, 0, stream>>>(x, pong, out, mm, wA, wB, bias);
}

// Round 13
// 822.422 us; speedup vs baseline: 1.0888x; 1.0493x over previous
//
#include <hip/hip_runtime.h>

#define HW 1024
#define NIMG 32
#define IMGPX ((size_t)HW * HW)
#define NELEM (NIMG * IMGPX)

typedef float f2 __attribute__((ext_vector_type(2)));

// region 128x64 per block, ring 6 -> out 116x52
#define RING 6
#define TOX 116
#define TOY 52
#define NBX 9
#define NBY 20
#define LSTR 136    // words per slot; col c(0..127)->word c; col -1 ->130; col 128 ->131
#define SLOTS 34    // boundary rows per buffer: -1, {0,3 mod 4}x16, 64
#define BUFW (SLOTS * LSTR)

// ---- float <-> order-preserving unsigned (for atomic min/max) ----
__device__ __forceinline__ unsigned f2su(float f) {
    unsigned u = __float_as_uint(f);
    return (u & 0x80000000u) ? ~u : (u | 0x80000000u);
}
__device__ __forceinline__ float s2f(unsigned u) {
    return __uint_as_float((u & 0x80000000u) ? (u & 0x7fffffffu) : ~u);
}

__global__ void mm_init(unsigned* mm) {
    mm[0] = 0xFFFFFFFFu;
    mm[1] = 0u;
}

__global__ __launch_bounds__(256) void mm_reduce(const float4* __restrict__ x,
                                                 unsigned* mm, int n4) {
    const int tid = threadIdx.x;
    int gid = blockIdx.x * blockDim.x + tid;
    const int stride = gridDim.x * blockDim.x;
    float vmin = 3.4e38f, vmax = -3.4e38f;
    for (int i = gid; i < n4; i += stride) {
        float4 v = x[i];
        vmin = fminf(vmin, fminf(fminf(v.x, v.y), fminf(v.z, v.w)));
        vmax = fmaxf(vmax, fmaxf(fmaxf(v.x, v.y), fmaxf(v.z, v.w)));
    }
    __shared__ float smin[256];
    __shared__ float smax[256];
    smin[tid] = vmin; smax[tid] = vmax;
    __syncthreads();
    for (int s = 128; s > 0; s >>= 1) {
        if (tid < s) {
            smin[tid] = fminf(smin[tid], smin[tid + s]);
            smax[tid] = fmaxf(smax[tid], smax[tid + s]);
        }
        __syncthreads();
    }
    if (tid == 0) {
        atomicMin(&mm[0], f2su(smin[0]));
        atomicMax(&mm[1], f2su(smax[0]));
    }
}

struct RowW { f2 P[2]; float L, R; };

// 512 threads: tx 0..31 owns 4 cols (2 f2 pairs), tyg 0..15 owns 4 rows.
// State in registers; double-buffered boundary slots (2 x 18.5 KB LDS).
// Split-barrier step loop: boundary rows (0,3) before the barrier, interior
// rows (1,2) after it -> ~half the conv work hides barrier/LDS-write latency.
template <int FIRST, int LAST>
__global__ __launch_bounds__(512) void fused_k(
    const float* __restrict__ x, const float* __restrict__ sin_,
    float* __restrict__ sout, const unsigned* __restrict__ mm,
    const float* __restrict__ wAp, const float* __restrict__ wBp,
    const float* __restrict__ biasp) {
#pragma clang fp contract(off)
    __shared__ float sb[2 * BUFW];
    const int tid = threadIdx.x;
    const int tx = tid & 31;
    const int tyg = tid >> 5;          // 0..15
    const int lane = tid & 63;
    const int laneL = (lane + 63) & 63;
    const int laneR = (lane + 1) & 63;
    const int r0 = tyg << 2;
    const int c0 = tx << 2;
    const int bx = (int)blockIdx.x, by = (int)blockIdx.y;
    const int ox = bx * TOX - RING;
    const int oy = by * TOY - RING;
    const size_t img = (size_t)blockIdx.z * IMGPX;
    const bool edgeX = (bx == 0) | (bx == NBX - 1);
    const bool edgeY = (by == 0) | (by == NBY - 1);
    const bool intr = !(edgeX | edgeY);

    const float xmin = s2f(mm[0]);
    const float xmax = s2f(mm[1]);
    const float scale = 2.0f / (xmax - xmin);
    const float b = biasp[0];

    auto ldSlot = [&](int wb) -> RowW {
        RowW o;
        const float4 q0 = *reinterpret_cast<const float4*>(&sb[wb + c0]);
        o.P[0] = f2{q0.x, q0.y}; o.P[1] = f2{q0.z, q0.w};
        const float fromL = __shfl(q0.w, laneL);
        const float fromR = __shfl(q0.x, laneR);
        o.L = (tx == 0) ? sb[wb + 130] : fromL;
        o.R = (tx == 31) ? sb[wb + 131] : fromR;
        return o;
    };

    float cf[9];
    // 9-term sequential row-major conv for pixel pair p in {0,1} (exact numpy order)
    auto conv9 = [&](const RowW& A, const RowW& B, const RowW& C, int p) -> f2 {
#pragma clang fp contract(off)
        f2 acc = f2{0.0f, 0.0f};
        f2 tl, tr;
        tl = f2{(p == 0) ? A.L : A.P[0].y, A.P[p].x};
        tr = f2{A.P[p].y, (p == 0) ? A.P[1].x : A.R};
        acc = acc + f2{cf[0], cf[0]} * tl;
        acc = acc + f2{cf[1], cf[1]} * A.P[p];
        acc = acc + f2{cf[2], cf[2]} * tr;
        tl = f2{(p == 0) ? B.L : B.P[0].y, B.P[p].x};
        tr = f2{B.P[p].y, (p == 0) ? B.P[1].x : B.R};
        acc = acc + f2{cf[3], cf[3]} * tl;
        acc = acc + f2{cf[4], cf[4]} * B.P[p];
        acc = acc + f2{cf[5], cf[5]} * tr;
        tl = f2{(p == 0) ? C.L : C.P[0].y, C.P[p].x};
        tr = f2{C.P[p].y, (p == 0) ? C.P[1].x : C.R};
        acc = acc + f2{cf[6], cf[6]} * tl;
        acc = acc + f2{cf[7], cf[7]} * C.P[p];
        acc = acc + f2{cf[8], cf[8]} * tr;
        return acc;
    };

    // ---- phase 1: xn rows -1..64 into linear slots 0..65 (spans BOTH buffers) ----
    if (intr) {
        for (int k = tid; k < 66 * 130; k += 512) {
            const int si = k / 130;
            const int cc = (k - si * 130) - 1;
            const int w = (cc == -1) ? 130 : ((cc == 128) ? 131 : cc);
            const float v =
                (x[img + (size_t)(oy + si - 1) * HW + (ox + cc)] - xmin) * scale - 1.0f;
            sb[si * LSTR + w] = v;
        }
    } else {
        for (int k = tid; k < 66 * 130; k += 512) {
            const int si = k / 130;
            const int cc = (k - si * 130) - 1;
            const int w = (cc == -1) ? 130 : ((cc == 128) ? 131 : cc);
            const int gr = oy + si - 1;
            const int gc = ox + cc;
            float v = 0.0f;
            if (gr >= 0 && gr < HW && gc >= 0 && gc < HW)
                v = (x[img + (size_t)gr * HW + gc] - xmin) * scale - 1.0f;
            sb[si * LSTR + w] = v;
        }
    }
    __syncthreads();

    // ---- phase 2: BU = conv(xn, B), all waves in one pass ----
#pragma unroll
    for (int i = 0; i < 9; ++i) cf[i] = wBp[i];
    f2 bu[4][2];
    {
        RowW prev = ldSlot((r0) * LSTR);
        RowW cur = ldSlot((r0 + 1) * LSTR);
#pragma unroll
        for (int i = 0; i < 4; ++i) {
            RowW nxt = ldSlot((r0 + 2 + i) * LSTR);
            bu[i][0] = conv9(prev, cur, nxt, 0);
            bu[i][1] = conv9(prev, cur, nxt, 1);
            prev = cur; cur = nxt;
        }
    }
    __syncthreads();

    // ---- phase 3: stage s into registers + frozen halos into BOTH buffers ----
    // slot map (per buffer): row -1 -> 0; row 4k -> 2k+1; row 4k+3 -> 2k+2; row 64 -> 33
    f2 res[4][2];
    float hS[4];  // tx==0: left halo col; tx==31: right halo col
    for (int k = tid; k < 324; k += 512) {
        int rr, cc;
        if (k < 260) { rr = (k < 130) ? -1 : 64; cc = (k % 130) - 1; }
        else {
            const int kk = k - 260;
            const int s = kk >> 1;            // 0..31
            rr = (s & 1) ? ((s >> 1) * 4 + 3) : ((s >> 1) * 4);
            cc = (kk & 1) ? 128 : -1;
        }
        const int w = (cc == -1) ? 130 : ((cc == 128) ? 131 : cc);
        const int slot = (rr == -1) ? 0 : ((rr == 64) ? 33 : ((rr >> 2) * 2 + 1 + (((rr & 3) == 3) ? 1 : 0)));
        float v = 0.0f;
        if (!FIRST) {
            const int gr = oy + rr, gc = ox + cc;
            if (gr >= 0 && gr < HW && gc >= 0 && gc < HW)
                v = sin_[img + (size_t)gr * HW + gc];
        }
        const int wo = slot * LSTR + w;
        sb[wo] = v;
        sb[BUFW + wo] = v;
    }
    if (FIRST) {
#pragma unroll
        for (int i = 0; i < 4; ++i) {
            hS[i] = 0.0f;
            res[i][0] = f2{0.0f, 0.0f};
            res[i][1] = f2{0.0f, 0.0f};
        }
    } else if (intr) {
#pragma unroll
        for (int i = 0; i < 4; ++i) {
            const float2* src = reinterpret_cast<const float2*>(
                &sin_[img + (size_t)(oy + r0 + i) * HW + ox + c0]);
            const float2 t0 = src[0];
            const float2 t1 = src[1];
            res[i][0] = f2{t0.x, t0.y};
            res[i][1] = f2{t1.x, t1.y};
            float hv = 0.0f;
            if (tx == 0) hv = sin_[img + (size_t)(oy + r0 + i) * HW + (ox - 1)];
            else if (tx == 31) hv = sin_[img + (size_t)(oy + r0 + i) * HW + (ox + 128)];
            hS[i] = hv;
        }
    } else {
#pragma unroll
        for (int i = 0; i < 4; ++i) {
            const int gr = oy + r0 + i;
            const bool rin = (gr >= 0) & (gr < HW);
#pragma unroll
            for (int cl = 0; cl < 4; ++cl) {
                const int gc = ox + c0 + cl;
                float v = 0.0f;
                if (rin && gc >= 0 && gc < HW) v = sin_[img + (size_t)gr * HW + gc];
                res[i][cl >> 1][cl & 1] = v;
            }
            float hv = 0.0f;
            if (tx == 0) {
                const int gc = ox - 1;
                if (rin && gc >= 0) hv = sin_[img + (size_t)gr * HW + gc];
            } else if (tx == 31) {
                const int gc = ox + 128;
                if (rin && gc < HW) hv = sin_[img + (size_t)gr * HW + gc];
            }
            hS[i] = hv;
        }
    }

    auto wrRow = [&](int bo, int i, int slot) {
        *reinterpret_cast<float4*>(&sb[bo + slot * LSTR + c0]) =
            make_float4(res[i][0].x, res[i][0].y, res[i][1].x, res[i][1].y);
    };
    wrRow(0, 0, 2 * tyg + 1);
    wrRow(0, 3, 2 * tyg + 2);
    __syncthreads();

    // ---- phase 4: 7 fused steps, split-barrier schedule ----
#pragma unroll
    for (int i = 0; i < 9; ++i) cf[i] = wAp[i];
    float mR[4];
#pragma unroll
    for (int i = 0; i < 4; ++i) {
        const int g = oy + r0 + i;
        mR[i] = (g >= 0 && g < HW) ? 1.0f : 0.0f;
    }
    f2 mC2[2];
#pragma unroll
    for (int p = 0; p < 2; ++p) {
        const int g0 = ox + c0 + 2 * p, g1 = g0 + 1;
        mC2[p] = f2{(g0 >= 0 && g0 < HW) ? 1.0f : 0.0f,
                    (g1 >= 0 && g1 < HW) ? 1.0f : 0.0f};
    }

    auto buildRow = [&](const f2 pr[2], float hs) -> RowW {
        RowW o;
        o.P[0] = pr[0]; o.P[1] = pr[1];
        const float fromL = __shfl(pr[1].y, laneL);
        const float fromR = __shfl(pr[0].x, laneR);
        o.L = (tx == 0) ? hs : fromL;
        o.R = (tx == 31) ? hs : fromR;
        return o;
    };

    // one output row i from old rows A,B,C (math identical to r10's rolling loop)
    auto stepRow = [&](int i, const RowW& A, const RowW& B, const RowW& C) {
        f2 n0 = conv9(A, B, C, 0);
        f2 n1 = conv9(A, B, C, 1);
        n0 = (n0 + f2{b, b}) + bu[i][0];
        n1 = (n1 + f2{b, b}) + bu[i][1];
        n0 = __builtin_elementwise_max(n0, f2{-1.0f, -1.0f});
        n0 = __builtin_elementwise_min(n0, f2{1.0f, 1.0f});
        n1 = __builtin_elementwise_max(n1, f2{-1.0f, -1.0f});
        n1 = __builtin_elementwise_min(n1, f2{1.0f, 1.0f});
        if (!intr) {
            n0 = n0 * f2{mR[i], mR[i]};
            n1 = n1 * f2{mR[i], mR[i]};
            n0 = n0 * mC2[0];
            n1 = n1 * mC2[1];
        }
        res[i][0] = n0; res[i][1] = n1;
    };

    const int slotM1 = (tyg == 0) ? 0 : 2 * tyg;
    const int slotP4 = (tyg == 15) ? 33 : 2 * tyg + 3;

#pragma unroll 1
    for (int t = 0; t < 7; ++t) {
        const int rdo = (t & 1) * BUFW;
        const int wro = BUFW - rdo;
        const RowW m1 = ldSlot(rdo + slotM1 * LSTR);   // old row r0-1
        const RowW p4 = ldSlot(rdo + slotP4 * LSTR);   // old row r0+4
        const RowW o0 = buildRow(res[0], hS[0]);
        const RowW o1 = buildRow(res[1], hS[1]);
        const RowW o2 = buildRow(res[2], hS[2]);
        const RowW o3 = buildRow(res[3], hS[3]);
        // boundary rows first, then publish + barrier
        stepRow(0, m1, o0, o1);
        stepRow(3, o2, o3, p4);
        wrRow(wro, 0, 2 * tyg + 1);
        wrRow(wro, 3, 2 * tyg + 2);
        __syncthreads();
        // interior rows in the barrier shadow
        stepRow(1, o0, o1, o2);
        stepRow(2, o1, o2, o3);
    }

    // ---- phase 5: store inner 116x52 tile ----
    const bool fullc = intr && (c0 >= RING) && (c0 + 3 < RING + TOX);
#pragma unroll
    for (int i = 0; i < 4; ++i) {
        const int r = r0 + i;
        if (r < RING || r >= RING + TOY) continue;
        const int gr = oy + r;
        if (gr >= HW) continue;  // gr >= 0 guaranteed (oy >= -6, r >= 6)
        if (fullc) {
            float2* dst = reinterpret_cast<float2*>(&sout[img + (size_t)gr * HW + ox + c0]);
            f2 v0 = res[i][0], v1 = res[i][1];
            if (LAST) {
                v0 = (v0 + f2{1.0f, 1.0f}) * f2{0.5f, 0.5f};
                v1 = (v1 + f2{1.0f, 1.0f}) * f2{0.5f, 0.5f};
            }
            dst[0] = make_float2(v0.x, v0.y);
            dst[1] = make_float2(v1.x, v1.y);
        } else {
#pragma unroll
            for (int cl = 0; cl < 4; ++cl) {
                const int c = c0 + cl;
                if (c < RING || c >= RING + TOX) continue;
                const int gc = ox + c;
                if (gc < 0 || gc >= HW) continue;
                float v = res[i][cl >> 1][cl & 1];
                if (LAST) v = (v + 1.0f) * 0.5f;
                sout[img + (size_t)gr * HW + gc] = v;
            }
        }
    }
}

extern "C" void kernel_launch(void* const* d_in, const int* in_sizes, int n_in,
                              void* d_out, int out_size, void* d_ws, size_t ws_size,
                              hipStream_t stream) {
    const float* x = (const float*)d_in[0];
    const float* wA = (const float*)d_in[1];
    const float* wB = (const float*)d_in[2];
    const float* bias = (const float*)d_in[3];
    float* out = (float*)d_out;
    unsigned* mm = (unsigned*)d_ws;
    float* pong = (float*)((char*)d_ws + 1024);  // 128 MiB f32 buffer

    mm_init<<<1, 1, 0, stream>>>(mm);
    mm_reduce<<<2048, 256, 0, stream>>>((const float4*)x, mm, (int)(NELEM / 4));

    dim3 grid(NBX, NBY, NIMG);
    // steps 1-7: zeros -> out (scratch); 8-14: out -> pong; 15-21: pong -> out
    fused_k<1, 0><<<grid, 512, 0, stream>>>(x, nullptr, out, mm, wA, wB, bias);
    fused_k<0, 0><<<grid, 512, 0, stream>>>(x, out, pong, mm, wA, wB, bias);
    fused_k<0, 1><<<grid, 512, 0, stream>>>(x, pong, out, mm, wA, wB, bias);
}

// Round 14
// 694.580 us; speedup vs baseline: 1.2892x; 1.1841x over previous
//
#include <hip/hip_runtime.h>

#define HW 1024
#define NIMG 32
#define IMGPX ((size_t)HW * HW)
#define NELEM (NIMG * IMGPX)

typedef float f2 __attribute__((ext_vector_type(2)));

// region 128x64 per block, ring 6 -> out 116x52
#define RING 6
#define TOX 116
#define TOY 52
#define NBX 9
#define NBY 20
#define LSTR 136    // words per slot; col c(0..127)->word c; col -1 ->130; col 128 ->131
#define SLOTS 34    // boundary rows per buffer: -1, {0,3 mod 4}x16, 64
#define BUFW (SLOTS * LSTR)

// ---- float <-> order-preserving unsigned (for atomic min/max) ----
__device__ __forceinline__ unsigned f2su(float f) {
    unsigned u = __float_as_uint(f);
    return (u & 0x80000000u) ? ~u : (u | 0x80000000u);
}
__device__ __forceinline__ float s2f(unsigned u) {
    return __uint_as_float((u & 0x80000000u) ? (u & 0x7fffffffu) : ~u);
}

__global__ void mm_init(unsigned* mm) {
    mm[0] = 0xFFFFFFFFu;
    mm[1] = 0u;
}

__global__ __launch_bounds__(256) void mm_reduce(const float4* __restrict__ x,
                                                 unsigned* mm, int n4) {
    const int tid = threadIdx.x;
    int gid = blockIdx.x * blockDim.x + tid;
    const int stride = gridDim.x * blockDim.x;
    float vmin = 3.4e38f, vmax = -3.4e38f;
    for (int i = gid; i < n4; i += stride) {
        float4 v = x[i];
        vmin = fminf(vmin, fminf(fminf(v.x, v.y), fminf(v.z, v.w)));
        vmax = fmaxf(vmax, fmaxf(fmaxf(v.x, v.y), fmaxf(v.z, v.w)));
    }
    __shared__ float smin[256];
    __shared__ float smax[256];
    smin[tid] = vmin; smax[tid] = vmax;
    __syncthreads();
    for (int s = 128; s > 0; s >>= 1) {
        if (tid < s) {
            smin[tid] = fminf(smin[tid], smin[tid + s]);
            smax[tid] = fmaxf(smax[tid], smax[tid + s]);
        }
        __syncthreads();
    }
    if (tid == 0) {
        atomicMin(&mm[0], f2su(smin[0]));
        atomicMax(&mm[1], f2su(smax[0]));
    }
}

struct RowW { f2 P[2]; float L, R; };

// 512 threads: tx 0..31 owns 4 cols (2 f2 pairs), tyg 0..15 owns 4 rows.
// BUMODE 0: compute BU locally (fallback). 1: compute + store output tile of
// BU to global (first kernel). 2: load BU from global (later kernels).
// FIRST kernels skip step 1: conv(0,A)==0 exactly -> s1 = clip(b + BU).
template <int FIRST, int LAST, int BUMODE>
__global__ __launch_bounds__(512) void fused_k(
    const float* __restrict__ x, const float* __restrict__ sin_,
    float* __restrict__ sout, float* __restrict__ bup,
    const unsigned* __restrict__ mm,
    const float* __restrict__ wAp, const float* __restrict__ wBp,
    const float* __restrict__ biasp) {
#pragma clang fp contract(off)
    __shared__ float sb[2 * BUFW];
    const int tid = threadIdx.x;
    const int tx = tid & 31;
    const int tyg = tid >> 5;          // 0..15
    const int lane = tid & 63;
    const int laneL = (lane + 63) & 63;
    const int laneR = (lane + 1) & 63;
    const int r0 = tyg << 2;
    const int c0 = tx << 2;
    const int bx = (int)blockIdx.x, by = (int)blockIdx.y;
    const int ox = bx * TOX - RING;
    const int oy = by * TOY - RING;
    const size_t img = (size_t)blockIdx.z * IMGPX;
    const bool edgeX = (bx == 0) | (bx == NBX - 1);
    const bool edgeY = (by == 0) | (by == NBY - 1);
    const bool intr = !(edgeX | edgeY);
    const bool fullc = intr && (c0 >= RING) && (c0 + 3 < RING + TOX);

    const float xmin = s2f(mm[0]);
    const float xmax = s2f(mm[1]);
    const float scale = 2.0f / (xmax - xmin);
    const float b = biasp[0];
    const f2 b2 = f2{b, b};

    float mR[4];
#pragma unroll
    for (int i = 0; i < 4; ++i) {
        const int g = oy + r0 + i;
        mR[i] = (g >= 0 && g < HW) ? 1.0f : 0.0f;
    }
    f2 mC2[2];
#pragma unroll
    for (int p = 0; p < 2; ++p) {
        const int g0 = ox + c0 + 2 * p, g1 = g0 + 1;
        mC2[p] = f2{(g0 >= 0 && g0 < HW) ? 1.0f : 0.0f,
                    (g1 >= 0 && g1 < HW) ? 1.0f : 0.0f};
    }

    auto ldSlot = [&](int wb) -> RowW {
        RowW o;
        const float4 q0 = *reinterpret_cast<const float4*>(&sb[wb + c0]);
        o.P[0] = f2{q0.x, q0.y}; o.P[1] = f2{q0.z, q0.w};
        const float fromL = __shfl(q0.w, laneL);
        const float fromR = __shfl(q0.x, laneR);
        o.L = (tx == 0) ? sb[wb + 130] : fromL;
        o.R = (tx == 31) ? sb[wb + 131] : fromR;
        return o;
    };

    float cf[9];
    // 9-term sequential row-major conv for pixel pair p in {0,1} (exact numpy order)
    auto conv9 = [&](const RowW& A, const RowW& B, const RowW& C, int p) -> f2 {
#pragma clang fp contract(off)
        f2 acc = f2{0.0f, 0.0f};
        f2 tl, tr;
        tl = f2{(p == 0) ? A.L : A.P[0].y, A.P[p].x};
        tr = f2{A.P[p].y, (p == 0) ? A.P[1].x : A.R};
        acc = acc + f2{cf[0], cf[0]} * tl;
        acc = acc + f2{cf[1], cf[1]} * A.P[p];
        acc = acc + f2{cf[2], cf[2]} * tr;
        tl = f2{(p == 0) ? B.L : B.P[0].y, B.P[p].x};
        tr = f2{B.P[p].y, (p == 0) ? B.P[1].x : B.R};
        acc = acc + f2{cf[3], cf[3]} * tl;
        acc = acc + f2{cf[4], cf[4]} * B.P[p];
        acc = acc + f2{cf[5], cf[5]} * tr;
        tl = f2{(p == 0) ? C.L : C.P[0].y, C.P[p].x};
        tr = f2{C.P[p].y, (p == 0) ? C.P[1].x : C.R};
        acc = acc + f2{cf[6], cf[6]} * tl;
        acc = acc + f2{cf[7], cf[7]} * C.P[p];
        acc = acc + f2{cf[8], cf[8]} * tr;
        return acc;
    };

    f2 bu[4][2];

    if (BUMODE != 2) {
        // ---- phase 1: xn rows -1..64 into linear slots 0..65 (both buffers) ----
        if (intr) {
            for (int k = tid; k < 66 * 130; k += 512) {
                const int si = k / 130;
                const int cc = (k - si * 130) - 1;
                const int w = (cc == -1) ? 130 : ((cc == 128) ? 131 : cc);
                const float v =
                    (x[img + (size_t)(oy + si - 1) * HW + (ox + cc)] - xmin) * scale - 1.0f;
                sb[si * LSTR + w] = v;
            }
        } else {
            for (int k = tid; k < 66 * 130; k += 512) {
                const int si = k / 130;
                const int cc = (k - si * 130) - 1;
                const int w = (cc == -1) ? 130 : ((cc == 128) ? 131 : cc);
                const int gr = oy + si - 1;
                const int gc = ox + cc;
                float v = 0.0f;
                if (gr >= 0 && gr < HW && gc >= 0 && gc < HW)
                    v = (x[img + (size_t)gr * HW + gc] - xmin) * scale - 1.0f;
                sb[si * LSTR + w] = v;
            }
        }
        __syncthreads();

        // ---- phase 2: BU = conv(xn, B) ----
#pragma unroll
        for (int i = 0; i < 9; ++i) cf[i] = wBp[i];
        {
            RowW prev = ldSlot((r0) * LSTR);
            RowW cur = ldSlot((r0 + 1) * LSTR);
#pragma unroll
            for (int i = 0; i < 4; ++i) {
                RowW nxt = ldSlot((r0 + 2 + i) * LSTR);
                bu[i][0] = conv9(prev, cur, nxt, 0);
                bu[i][1] = conv9(prev, cur, nxt, 1);
                prev = cur; cur = nxt;
            }
        }
        __syncthreads();

        if (BUMODE == 1) {
            // store output-tile portion of BU (tiles partition the image; every
            // writer computes the exact same bits -> deterministic)
#pragma unroll
            for (int i = 0; i < 4; ++i) {
                const int r = r0 + i;
                if (r < RING || r >= RING + TOY) continue;
                const int gr = oy + r;
                if (gr >= HW) continue;
                if (fullc) {
                    *reinterpret_cast<float4*>(&bup[img + (size_t)gr * HW + ox + c0]) =
                        make_float4(bu[i][0].x, bu[i][0].y, bu[i][1].x, bu[i][1].y);
                } else {
#pragma unroll
                    for (int cl = 0; cl < 4; ++cl) {
                        const int c = c0 + cl;
                        if (c < RING || c >= RING + TOX) continue;
                        const int gc = ox + c;
                        if (gc < 0 || gc >= HW) continue;
                        bup[img + (size_t)gr * HW + gc] = bu[i][cl >> 1][cl & 1];
                    }
                }
            }
        }
    } else {
        // ---- BUMODE 2: load BU from global (clamped addr; clamped values only
        // reach out-of-image cells, which are masked to zero) ----
        if (intr) {
#pragma unroll
            for (int i = 0; i < 4; ++i) {
                const float4 q = *reinterpret_cast<const float4*>(
                    &bup[img + (size_t)(oy + r0 + i) * HW + ox + c0]);
                bu[i][0] = f2{q.x, q.y};
                bu[i][1] = f2{q.z, q.w};
            }
        } else {
#pragma unroll
            for (int i = 0; i < 4; ++i) {
                int gr = oy + r0 + i;
                gr = (gr < 0) ? 0 : ((gr >= HW) ? HW - 1 : gr);
#pragma unroll
                for (int cl = 0; cl < 4; ++cl) {
                    int gc = ox + c0 + cl;
                    gc = (gc < 0) ? 0 : ((gc >= HW) ? HW - 1 : gc);
                    bu[i][cl >> 1][cl & 1] = bup[img + (size_t)gr * HW + gc];
                }
            }
        }
    }

    // ---- phase 3: stage s + frozen halos into BOTH buffers ----
    // slot map (per buffer): row -1 -> 0; row 4k -> 2k+1; row 4k+3 -> 2k+2; row 64 -> 33
    f2 res[4][2];
    float hS[4];  // tx==0: left halo col; tx==31: right halo col
    for (int k = tid; k < 324; k += 512) {
        int rr, cc;
        if (k < 260) { rr = (k < 130) ? -1 : 64; cc = (k % 130) - 1; }
        else {
            const int kk = k - 260;
            const int s = kk >> 1;            // 0..31
            rr = (s & 1) ? ((s >> 1) * 4 + 3) : ((s >> 1) * 4);
            cc = (kk & 1) ? 128 : -1;
        }
        const int w = (cc == -1) ? 130 : ((cc == 128) ? 131 : cc);
        const int slot = (rr == -1) ? 0 : ((rr == 64) ? 33 : ((rr >> 2) * 2 + 1 + (((rr & 3) == 3) ? 1 : 0)));
        float v = 0.0f;
        if (!FIRST) {
            const int gr = oy + rr, gc = ox + cc;
            if (gr >= 0 && gr < HW && gc >= 0 && gc < HW)
                v = sin_[img + (size_t)gr * HW + gc];
        }
        const int wo = slot * LSTR + w;
        sb[wo] = v;
        sb[BUFW + wo] = v;
    }
    if (FIRST) {
        // skip step 1: conv(s0,A) == 0 exactly and (0+b) == b bitwise, so
        // s1 = clip(b + BU) (then zero-masked outside image, as reference pad)
#pragma unroll
        for (int i = 0; i < 4; ++i) {
            hS[i] = 0.0f;  // frozen halo keeps s0 = 0 (stale-by-design, ring absorbs)
#pragma unroll
            for (int p = 0; p < 2; ++p) {
                f2 v = b2 + bu[i][p];
                v = __builtin_elementwise_max(v, f2{-1.0f, -1.0f});
                v = __builtin_elementwise_min(v, f2{1.0f, 1.0f});
                if (!intr) {
                    v = v * f2{mR[i], mR[i]};
                    v = v * mC2[p];
                }
                res[i][p] = v;
            }
        }
    } else if (intr) {
#pragma unroll
        for (int i = 0; i < 4; ++i) {
            const float2* src = reinterpret_cast<const float2*>(
                &sin_[img + (size_t)(oy + r0 + i) * HW + ox + c0]);
            const float2 t0 = src[0];
            const float2 t1 = src[1];
            res[i][0] = f2{t0.x, t0.y};
            res[i][1] = f2{t1.x, t1.y};
            float hv = 0.0f;
            if (tx == 0) hv = sin_[img + (size_t)(oy + r0 + i) * HW + (ox - 1)];
            else if (tx == 31) hv = sin_[img + (size_t)(oy + r0 + i) * HW + (ox + 128)];
            hS[i] = hv;
        }
    } else {
#pragma unroll
        for (int i = 0; i < 4; ++i) {
            const int gr = oy + r0 + i;
            const bool rin = (gr >= 0) & (gr < HW);
#pragma unroll
            for (int cl = 0; cl < 4; ++cl) {
                const int gc = ox + c0 + cl;
                float v = 0.0f;
                if (rin && gc >= 0 && gc < HW) v = sin_[img + (size_t)gr * HW + gc];
                res[i][cl >> 1][cl & 1] = v;
            }
            float hv = 0.0f;
            if (tx == 0) {
                const int gc = ox - 1;
                if (rin && gc >= 0) hv = sin_[img + (size_t)gr * HW + gc];
            } else if (tx == 31) {
                const int gc = ox + 128;
                if (rin && gc < HW) hv = sin_[img + (size_t)gr * HW + gc];
            }
            hS[i] = hv;
        }
    }

    auto wrRow = [&](int bo, int i, int slot) {
        *reinterpret_cast<float4*>(&sb[bo + slot * LSTR + c0]) =
            make_float4(res[i][0].x, res[i][0].y, res[i][1].x, res[i][1].y);
    };
    wrRow(0, 0, 2 * tyg + 1);
    wrRow(0, 3, 2 * tyg + 2);
    __syncthreads();

    // ---- phase 4: fused steps, split-barrier schedule ----
#pragma unroll
    for (int i = 0; i < 9; ++i) cf[i] = wAp[i];

    auto buildRow = [&](const f2 pr[2], float hs) -> RowW {
        RowW o;
        o.P[0] = pr[0]; o.P[1] = pr[1];
        const float fromL = __shfl(pr[1].y, laneL);
        const float fromR = __shfl(pr[0].x, laneR);
        o.L = (tx == 0) ? hs : fromL;
        o.R = (tx == 31) ? hs : fromR;
        return o;
    };

    auto stepRow = [&](int i, const RowW& A, const RowW& B, const RowW& C) {
        f2 n0 = conv9(A, B, C, 0);
        f2 n1 = conv9(A, B, C, 1);
        n0 = (n0 + b2) + bu[i][0];
        n1 = (n1 + b2) + bu[i][1];
        n0 = __builtin_elementwise_max(n0, f2{-1.0f, -1.0f});
        n0 = __builtin_elementwise_min(n0, f2{1.0f, 1.0f});
        n1 = __builtin_elementwise_max(n1, f2{-1.0f, -1.0f});
        n1 = __builtin_elementwise_min(n1, f2{1.0f, 1.0f});
        if (!intr) {
            n0 = n0 * f2{mR[i], mR[i]};
            n1 = n1 * f2{mR[i], mR[i]};
            n0 = n0 * mC2[0];
            n1 = n1 * mC2[1];
        }
        res[i][0] = n0; res[i][1] = n1;
    };

    const int slotM1 = (tyg == 0) ? 0 : 2 * tyg;
    const int slotP4 = (tyg == 15) ? 33 : 2 * tyg + 3;
    const int NST = FIRST ? 6 : 7;

#pragma unroll 1
    for (int t = 0; t < NST; ++t) {
        const int rdo = (t & 1) * BUFW;
        const int wro = BUFW - rdo;
        const RowW m1 = ldSlot(rdo + slotM1 * LSTR);   // old row r0-1
        const RowW p4 = ldSlot(rdo + slotP4 * LSTR);   // old row r0+4
        const RowW o0 = buildRow(res[0], hS[0]);
        const RowW o1 = buildRow(res[1], hS[1]);
        const RowW o2 = buildRow(res[2], hS[2]);
        const RowW o3 = buildRow(res[3], hS[3]);
        // boundary rows first, then publish + barrier
        stepRow(0, m1, o0, o1);
        stepRow(3, o2, o3, p4);
        wrRow(wro, 0, 2 * tyg + 1);
        wrRow(wro, 3, 2 * tyg + 2);
        __syncthreads();
        // interior rows in the barrier shadow
        stepRow(1, o0, o1, o2);
        stepRow(2, o1, o2, o3);
    }

    // ---- phase 5: store inner 116x52 tile ----
#pragma unroll
    for (int i = 0; i < 4; ++i) {
        const int r = r0 + i;
        if (r < RING || r >= RING + TOY) continue;
        const int gr = oy + r;
        if (gr >= HW) continue;  // gr >= 0 guaranteed (oy >= -6, r >= 6)
        if (fullc) {
            float2* dst = reinterpret_cast<float2*>(&sout[img + (size_t)gr * HW + ox + c0]);
            f2 v0 = res[i][0], v1 = res[i][1];
            if (LAST) {
                v0 = (v0 + f2{1.0f, 1.0f}) * f2{0.5f, 0.5f};
                v1 = (v1 + f2{1.0f, 1.0f}) * f2{0.5f, 0.5f};
            }
            dst[0] = make_float2(v0.x, v0.y);
            dst[1] = make_float2(v1.x, v1.y);
        } else {
#pragma unroll
            for (int cl = 0; cl < 4; ++cl) {
                const int c = c0 + cl;
                if (c < RING || c >= RING + TOX) continue;
                const int gc = ox + c;
                if (gc < 0 || gc >= HW) continue;
                float v = res[i][cl >> 1][cl & 1];
                if (LAST) v = (v + 1.0f) * 0.5f;
                sout[img + (size_t)gr * HW + gc] = v;
            }
        }
    }
}

extern "C" void kernel_launch(void* const* d_in, const int* in_sizes, int n_in,
                              void* d_out, int out_size, void* d_ws, size_t ws_size,
                              hipStream_t stream) {
    const float* x = (const float*)d_in[0];
    const float* wA = (const float*)d_in[1];
    const float* wB = (const float*)d_in[2];
    const float* bias = (const float*)d_in[3];
    float* out = (float*)d_out;
    unsigned* mm = (unsigned*)d_ws;
    float* pong = (float*)((char*)d_ws + 1024);  // 128 MiB s ping buffer
    float* bub = pong + NELEM;                   // 128 MiB BU buffer (if it fits)

    mm_init<<<1, 1, 0, stream>>>(mm);
    mm_reduce<<<2048, 256, 0, stream>>>((const float4*)x, mm, (int)(NELEM / 4));

    dim3 grid(NBX, NBY, NIMG);
    const size_t needBU = 1024 + 2ull * NELEM * sizeof(float);
    if (ws_size >= needBU) {
        // k1 computes+stores BU, skips step 1; k2/k3 load BU (no staging)
        fused_k<1, 0, 1><<<grid, 512, 0, stream>>>(x, nullptr, out, bub, mm, wA, wB, bias);
        fused_k<0, 0, 2><<<grid, 512, 0, stream>>>(x, out, pong, bub, mm, wA, wB, bias);
        fused_k<0, 1, 2><<<grid, 512, 0, stream>>>(x, pong, out, bub, mm, wA, wB, bias);
    } else {
        // fallback: every kernel computes its own BU (r13 scheme + skip step 1)
        fused_k<1, 0, 0><<<grid, 512, 0, stream>>>(x, nullptr, out, nullptr, mm, wA, wB, bias);
        fused_k<0, 0, 0><<<grid, 512, 0, stream>>>(x, out, pong, nullptr, mm, wA, wB, bias);
        fused_k<0, 1, 0><<<grid, 512, 0, stream>>>(x, pong, out, nullptr, mm, wA, wB, bias);
    }
}